// Round 10
// baseline (84.099 us; speedup 1.0000x reference)
//
#include <hip/hip_runtime.h>

// Profile-HMM forward + KLD, MI355X.
// v10 = v9 (linear-space, 2 columns/step, 191 effective steps) with the
// scale-coherence fix: neighbor exponent E travels on its OWN DPP channel
// (always current), symbols on a separate delay register. v9's bug: E was
// packed in a meta word not refreshed at rescale -> consumers applied a
// stale scale tag to post-rescale state on the first step of every group.
//
// One wave per batch element; lane i owns states k1=2i+1, k2=2i+2.
// At step s, lane i advances by 2 columns: c=2(s-i)-1, c+1.
// Cross-lane per step: 8 DPP wave_shr:1 (mid M/I/D @ col c, end M/I/D @ col
// c+1, E, syms). Col-0 delete chain precomputed in closed form. Range via
// per-lane exponent E, rescaled every 2 steps (exact power-of-2 shifts).

typedef float v2f __attribute__((ext_vector_type(2)));

constexpr float LOG2E = 1.4426950408889634f;
constexpr float LN2   = 0.6931471805599453f;

__device__ __forceinline__ float exp2_hw(float x){ return __builtin_amdgcn_exp2f(x); }
__device__ __forceinline__ float log2_hw(float x){ return __builtin_amdgcn_logf(x); }
__device__ __forceinline__ float ldx(float x,int e){ return __builtin_amdgcn_ldexpf(x,e); }
__device__ __forceinline__ int   fxe(float x){ return __builtin_amdgcn_frexp_expf(x); }
// DPP wave_shr:1 — lane i gets lane i-1's src; lane 0 gets old_.
__device__ __forceinline__ int   dppi(int o,int s){ return __builtin_amdgcn_update_dpp(o,s,0x138,0xF,0xF,false); }
__device__ __forceinline__ float dppf(float o,float s){ return __int_as_float(dppi(__float_as_int(o),__float_as_int(s))); }

// transitions: (B, 129, 7)  M2M=0 M2I=1 M2D=2 I2M=3 I2I=4 D2M=5 D2D=6
// emissions:   (B, 128, 4);  tokens: (B, 256) int32 in [0,4)
__global__ __launch_bounds__(64) void phmm_fwd(const int* __restrict__ tokens,
                                               const float* __restrict__ trans,
                                               const float* __restrict__ emis,
                                               float* __restrict__ nll_out)
{
    const int b = blockIdx.x;
    const int i = threadIdx.x;
    const bool lane0 = (i == 0);

    const float* ab = trans + (size_t)b * 903;
    const int r0 = (2*i)*7, r1 = (2*i+1)*7, r2 = (2*i+2)*7;

    // Linear-space params (exp hoisted to init).
    const float tmm0 = exp2_hw(ab[r0+0]*LOG2E);
    const float tim0 = exp2_hw(ab[r0+3]*LOG2E);
    const float tdm0 = exp2_hw(ab[r0+5]*LOG2E);
    const float tmd0 = exp2_hw(ab[r0+2]*LOG2E);
    const float tdd0 = exp2_hw(ab[r0+6]*LOG2E);
    const float tmm1 = exp2_hw(ab[r1+0]*LOG2E);
    const float tim1 = exp2_hw(ab[r1+3]*LOG2E);
    const float tdm1 = exp2_hw(ab[r1+5]*LOG2E);
    const float tmd1 = exp2_hw(ab[r1+2]*LOG2E);
    const float tdd1 = exp2_hw(ab[r1+6]*LOG2E);
    const float tmi1 = 0.25f*exp2_hw(ab[r1+1]*LOG2E);
    const float tii1 = 0.25f*exp2_hw(ab[r1+4]*LOG2E);
    const float tmi2 = 0.25f*exp2_hw(ab[r2+1]*LOG2E);
    const float tii2 = 0.25f*exp2_hw(ab[r2+4]*LOG2E);
    const float q1g  = 0.25f*exp2_hw(ab[1]*LOG2E);   // fI0[1]
    const float gg   = 0.25f*exp2_hw(ab[4]*LOG2E);   // fI0 geometric link
    const float tKmm = exp2_hw(ab[128*7+0]*LOG2E);
    const float tKim = exp2_hw(ab[128*7+3]*LOG2E);
    const float tKdm = exp2_hw(ab[128*7+5]*LOG2E);

    const v2f tMM = {tmm0, tmm1}, tIM = {tim0, tim1}, tDM = {tdm0, tdm1};
    const v2f tMI = {tmi1, tmi2}, tII = {tii1, tii2};

    const float4* eb = (const float4*)(emis + (size_t)b*512);
    float4 el1 = eb[2*i], el2 = eb[2*i+1];
    el1.x=exp2_hw(el1.x*LOG2E); el1.y=exp2_hw(el1.y*LOG2E);
    el1.z=exp2_hw(el1.z*LOG2E); el1.w=exp2_hw(el1.w*LOG2E);
    el2.x=exp2_hw(el2.x*LOG2E); el2.y=exp2_hw(el2.y*LOG2E);
    el2.z=exp2_hw(el2.z*LOG2E); el2.w=exp2_hw(el2.w*LOG2E);

    const int4 ts = ((const int4*)(tokens + (size_t)b*256))[i];

    // Col-0 delete chain, closed form: log2 fD[k][0] = lmd(row0) + sum ldd(rows 1..k-1).
    const float ldd0 = ab[r0+6]*LOG2E;   // row 2i D2D (log2)
    const float ldd1 = ab[r1+6]*LOG2E;   // row 2i+1
    const float lmd0b = ab[2]*LOG2E;     // row 0 M2D (uniform scalar)
    float incl = (lane0 ? 0.0f : ldd0) + ldd1;  // rows {2i,2i+1} (lane0: row1 only)
    #pragma unroll
    for (int d = 1; d < 64; d <<= 1) {
        float t = __shfl_up(incl, d);
        if (i >= d) incl += t;
    }
    float exPre = __shfl_up(incl, 1);
    if (lane0) exPre = 0.0f;             // rows 1..2i-1
    const float g1 = lmd0b + exPre + (lane0 ? 0.0f : ldd0); // log2 fD[2i+1][0]
    const float g2 = g1 + ldd1;                             // log2 fD[2i+2][0]

    int E = (int)floorf(fmaxf(g1, g2));  // per-lane scale anchor
    v2f cM = {0.0f, 0.0f}, cI = {0.0f, 0.0f};
    v2f cD = {exp2_hw(g1 - (float)E), exp2_hw(g2 - (float)E)};
    float emM = 0.0f, emI = 0.0f, emD = 0.0f;   // mid exports (col c, row k2)
    float pM = 0.0f, pI = 0.0f, pD = 0.0f; int pE = 0; // saved end (col c-1), raw
    float u = 0.0f; int EI0 = 0;                // fI0[2s-2], scale 2^EI0 (uniform)
    int symq = 0;                               // symbol-pair delay register
    const float m00 = ldx(1.0f, -E);            // fM[0][0] in lane0's scale

    // One 2-col step: cols c = 2s-1-2i, c+1. sm1 = s-1.
    auto step = [&](int fresh, bool isS1, int sm1) {
        const float qmM = dppf(0.0f, emM);   // neighbor k0 @ col c
        const float qmI = dppf(0.0f, emI);
        const float qmD = dppf(0.0f, emD);
        const float qeM = dppf(0.0f, cM.y);  // neighbor k0 @ col c+1
        const float qeI = dppf(0.0f, cI.y);
        const float qeD = dppf(0.0f, cD.y);
        const int   qE  = dppi(0, E);        // neighbor CURRENT scale
        const int qsym  = dppi(fresh, symq); // symbol delay line
        const float sq = ldx(1.0f, qE - E);  // neighbor scale -> own
        const float sp = ldx(1.0f, pE - E);  // saved scale -> own
        const float v = isS1 ? q1g : gg * u; // fI0[2s-1]
        float mM = qmM * sq, mI = qmI * sq, mD = qmD * sq;
        float eM_ = qeM * sq, eD_ = qeD * sq;
        float PM = pM * sp, PI = pI * sp, PD = pD * sp;
        if (lane0) {                          // virtual row 0 boundary
            PM = isS1 ? m00 : 0.0f;           // fM[0][c-1]
            PI = ldx(u, EI0 - E);             // fI[0][c-1]
            PD = 0.0f;
            mM = 0.0f; mD = 0.0f;
            mI = ldx(v, EI0 - E);             // fI[0][c]
            eM_ = 0.0f; eD_ = 0.0f;
        }
        const int sa = qsym & 3, sb = (qsym >> 2) & 3;
        const float e1c = (sa & 2) ? ((sa & 1) ? el1.w : el1.z) : ((sa & 1) ? el1.y : el1.x);
        const float e2c = (sa & 2) ? ((sa & 1) ? el2.w : el2.z) : ((sa & 1) ? el2.y : el2.x);
        const float e1d = (sb & 2) ? ((sb & 1) ? el1.w : el1.z) : ((sb & 1) ? el1.y : el1.x);
        const float e2d = (sb & 2) ? ((sb & 1) ? el2.w : el2.z) : ((sb & 1) ? el2.y : el2.x);
        // ---- col c (from state @ c-1)
        v2f A = {PM, cM.x}, B = {PI, cI.x}, C = {PD, cD.x};
        v2f nM = tMM*A + tIM*B + tDM*C;
        nM.x *= e1c; nM.y *= e2c;
        v2f nI = tMI*cM + tII*cI;
        const float nD1 = fmaf(tmd0, mM, tdd0*mD);
        const float nD2 = fmaf(tmd1, nM.x, tdd1*nD1);
        // ---- col c+1
        v2f A2 = {mM, nM.x}, B2 = {mI, nI.x}, C2 = {mD, nD1};
        v2f nMb = tMM*A2 + tIM*B2 + tDM*C2;
        nMb.x *= e1d; nMb.y *= e2d;
        v2f nIb = tMI*nM + tII*nI;
        const float nD1b = fmaf(tmd0, eM_, tdd0*eD_);
        const float nD2b = fmaf(tmd1, nMb.x, tdd1*nD1b);
        // exports (unmasked: consumer-active => producer-was-active) & state (masked)
        emM = nM.y; emI = nI.y; emD = nD2;
        const bool act = ((unsigned)(sm1 - i)) < 128u;  // 1 <= s-i <= 128
        cM.x = act ? nMb.x : cM.x;  cM.y = act ? nMb.y : cM.y;
        cI.x = act ? nIb.x : cI.x;  cI.y = act ? nIb.y : cI.y;
        cD.x = act ? nD1b  : cD.x;  cD.y = act ? nD2b  : cD.y;
        pM = qeM; pI = qeI; pD = qeD; pE = qE;  // raw copies, scale-tagged by pE
        symq = qsym;
        u = gg * v;                              // fI0[2s]
    };

    auto rescale = [&]() {
        const float anc = fmaxf(fmaxf(fmaxf(cM.x, cM.y), fmaxf(cI.x, cI.y)),
                                fmaxf(cD.x, cD.y));
        const int e = fxe(anc);
        E += e;
        const float sE = ldx(1.0f, -e);
        cM *= sE; cI *= sE; cD *= sE;
        emM *= sE; emI *= sE; emD *= sE;
        const int eI = fxe(u); EI0 += eI; u = ldx(u, -eI);
    };

    // 96 groups x 2 steps: s = 1..192 (lane 63's last active step is 191).
    #pragma unroll 1
    for (int n = 0; n < 96; ++n) {
        const int sel = n & 63;   // group n consumes tokens 4n..4n+3 (n>63: unused)
        const int t0 = __builtin_amdgcn_readlane(ts.x, sel);
        const int t1 = __builtin_amdgcn_readlane(ts.y, sel);
        const int t2 = __builtin_amdgcn_readlane(ts.z, sel);
        const int t3 = __builtin_amdgcn_readlane(ts.w, sel);
        step(t0 | (t1 << 2), n == 0, 2*n);      // s = 2n+1
        step(t2 | (t3 << 2), false,  2*n + 1);  // s = 2n+2
        rescale();
    }

    // lane 63 holds k=127,128 @ col 256; .y = k=128.
    const float fin = fmaf(tKdm, cD.y, fmaf(tKim, cI.y, tKmm*cM.y));
    if (i == 63) nll_out[b] = -(log2_hw(fin) + (float)E)*LN2;
}

__global__ __launch_bounds__(256) void phmm_finish(const float* __restrict__ nll,
                                                   const float* __restrict__ mus,
                                                   const float* __restrict__ logvars,
                                                   float* __restrict__ out)
{
    const int tid = threadIdx.x;
    float acc = 0.0f;
    for (int idx = tid; idx < 512; idx += 256) acc += nll[idx];
    for (int idx = tid; idx < 8192; idx += 256) {
        const float mu = mus[idx], lv = logvars[idx];
        acc -= 0.5f * (1.0f + lv - mu * mu - exp2_hw(lv * LOG2E));
    }
    #pragma unroll
    for (int off = 32; off >= 1; off >>= 1) acc += __shfl_down(acc, off);
    __shared__ float red[4];
    if ((tid & 63) == 0) red[tid >> 6] = acc;
    __syncthreads();
    if (tid == 0) out[0] = (red[0] + red[1] + red[2] + red[3]) * (1.0f / 512.0f);
}

extern "C" void kernel_launch(void* const* d_in, const int* in_sizes, int n_in,
                              void* d_out, int out_size, void* d_ws, size_t ws_size,
                              hipStream_t stream)
{
    const int*   tokens  = (const int*)d_in[0];   // (512, 256) int32
    const float* trans   = (const float*)d_in[1]; // (512, 129, 7) f32
    const float* emis    = (const float*)d_in[2]; // (512, 128, 4) f32
    const float* mus     = (const float*)d_in[3]; // (512, 16) f32
    const float* logvars = (const float*)d_in[4]; // (512, 16) f32
    float* nll = (float*)d_ws;                    // 512 floats scratch

    phmm_fwd<<<dim3(512), dim3(64), 0, stream>>>(tokens, trans, emis, nll);
    phmm_finish<<<dim3(1), dim3(256), 0, stream>>>(nll, mus, logvars, (float*)d_out);
}

// Round 11
// 52.429 us; speedup vs baseline: 1.6040x; 1.6040x over previous
//
#include <hip/hip_runtime.h>

// Profile-HMM forward + KLD, MI355X.
// v11 = v10 (linear-space, 2 columns/step, E on own DPP channel) with the
// step/rescale LAMBDAS replaced by MACROS. v10's lambdas captured ~30 locals
// by reference; clang failed SROA -> alloca -> AMDGPU PromoteAlloca put the
// whole DP state in LDS (LDS_Block_Size=2048, 1.7M bank conflicts, VGPR=32).
// Macros over plain locals keep state in VGPRs (v8 idiom: LDS=0).

typedef float v2f __attribute__((ext_vector_type(2)));

constexpr float LOG2E = 1.4426950408889634f;
constexpr float LN2   = 0.6931471805599453f;

__device__ __forceinline__ float exp2_hw(float x){ return __builtin_amdgcn_exp2f(x); }
__device__ __forceinline__ float log2_hw(float x){ return __builtin_amdgcn_logf(x); }
__device__ __forceinline__ float ldx(float x,int e){ return __builtin_amdgcn_ldexpf(x,e); }
__device__ __forceinline__ int   fxe(float x){ return __builtin_amdgcn_frexp_expf(x); }
// DPP wave_shr:1 — lane i gets lane i-1's src; lane 0 gets old_.
__device__ __forceinline__ int   dppi(int o,int s){ return __builtin_amdgcn_update_dpp(o,s,0x138,0xF,0xF,false); }
__device__ __forceinline__ float dppf(float o,float s){ return __int_as_float(dppi(__float_as_int(o),__float_as_int(s))); }

// One 2-col step: cols c = 2*SM1+1-2i, c+1. All operands are named locals.
#define STEP(FRESH, ISS1, SM1) do {                                            \
    const float qmM = dppf(0.0f, emM);   /* neighbor k0 @ col c   */           \
    const float qmI = dppf(0.0f, emI);                                         \
    const float qmD = dppf(0.0f, emD);                                         \
    const float qeM = dppf(0.0f, cMy);   /* neighbor k0 @ col c+1 */           \
    const float qeI = dppf(0.0f, cIy);                                         \
    const float qeD = dppf(0.0f, cDy);                                         \
    const int   qE  = dppi(0, E);        /* neighbor CURRENT scale */          \
    const int qsym  = dppi((FRESH), symq);                                     \
    const float sq = ldx(1.0f, qE - E);                                        \
    const float sp = ldx(1.0f, pE - E);                                        \
    const float v = (ISS1) ? q1g : gg * u;  /* fI0[2s-1] */                    \
    float mM = qmM * sq, mI = qmI * sq, mD = qmD * sq;                         \
    float eM_ = qeM * sq, eD_ = qeD * sq;                                      \
    float PM = pM * sp, PI = pI * sp, PD = pD * sp;                            \
    if (lane0) {                          /* virtual row 0 boundary */         \
        PM = (ISS1) ? m00 : 0.0f;                                              \
        PI = ldx(u, EI0 - E);                                                  \
        PD = 0.0f;                                                             \
        mM = 0.0f; mD = 0.0f;                                                  \
        mI = ldx(v, EI0 - E);                                                  \
        eM_ = 0.0f; eD_ = 0.0f;                                                \
    }                                                                          \
    const int sa = qsym & 3, sb = (qsym >> 2) & 3;                             \
    const float e1c = (sa & 2) ? ((sa & 1) ? el1.w : el1.z) : ((sa & 1) ? el1.y : el1.x); \
    const float e2c = (sa & 2) ? ((sa & 1) ? el2.w : el2.z) : ((sa & 1) ? el2.y : el2.x); \
    const float e1d = (sb & 2) ? ((sb & 1) ? el1.w : el1.z) : ((sb & 1) ? el1.y : el1.x); \
    const float e2d = (sb & 2) ? ((sb & 1) ? el2.w : el2.z) : ((sb & 1) ? el2.y : el2.x); \
    /* col c (from state @ c-1) */                                             \
    const float nM1 = e1c * fmaf(tdm0, PD,  fmaf(tim0, PI,  tmm0 * PM));       \
    const float nM2 = e2c * fmaf(tdm1, cDx, fmaf(tim1, cIx, tmm1 * cMx));      \
    const float nI1 = fmaf(tmi1, cMx, tii1 * cIx);                             \
    const float nI2 = fmaf(tmi2, cMy, tii2 * cIy);                             \
    const float nD1 = fmaf(tmd0, mM, tdd0 * mD);                               \
    const float nD2 = fmaf(tmd1, nM1, tdd1 * nD1);                             \
    /* col c+1 */                                                              \
    const float nM1b = e1d * fmaf(tdm0, mD,  fmaf(tim0, mI,  tmm0 * mM));      \
    const float nM2b = e2d * fmaf(tdm1, nD1, fmaf(tim1, nI1, tmm1 * nM1));     \
    const float nI1b = fmaf(tmi1, nM1, tii1 * nI1);                            \
    const float nI2b = fmaf(tmi2, nM2, tii2 * nI2);                            \
    const float nD1b = fmaf(tmd0, eM_, tdd0 * eD_);                            \
    const float nD2b = fmaf(tmd1, nM1b, tdd1 * nD1b);                          \
    emM = nM2; emI = nI2; emD = nD2;      /* mid exports (unmasked) */         \
    const bool act = ((unsigned)((SM1) - i)) < 128u;                           \
    cMx = act ? nM1b : cMx;  cMy = act ? nM2b : cMy;                           \
    cIx = act ? nI1b : cIx;  cIy = act ? nI2b : cIy;                           \
    cDx = act ? nD1b : cDx;  cDy = act ? nD2b : cDy;                           \
    pM = qeM; pI = qeI; pD = qeD; pE = qE;                                     \
    symq = qsym;                                                               \
    u = gg * v;                            /* fI0[2s] */                       \
} while (0)

#define RESCALE do {                                                           \
    const float anc = fmaxf(fmaxf(fmaxf(cMx, cMy), fmaxf(cIx, cIy)),           \
                            fmaxf(cDx, cDy));                                  \
    const int e = fxe(anc);                                                    \
    E += e;                                                                    \
    const float sE = ldx(1.0f, -e);                                            \
    cMx *= sE; cMy *= sE; cIx *= sE; cIy *= sE; cDx *= sE; cDy *= sE;          \
    emM *= sE; emI *= sE; emD *= sE;                                           \
    const int eI = fxe(u); EI0 += eI; u = ldx(u, -eI);                         \
} while (0)

// transitions: (B, 129, 7)  M2M=0 M2I=1 M2D=2 I2M=3 I2I=4 D2M=5 D2D=6
// emissions:   (B, 128, 4);  tokens: (B, 256) int32 in [0,4)
__global__ __launch_bounds__(64) void phmm_fwd(const int* __restrict__ tokens,
                                               const float* __restrict__ trans,
                                               const float* __restrict__ emis,
                                               float* __restrict__ nll_out)
{
    const int b = blockIdx.x;
    const int i = threadIdx.x;
    const bool lane0 = (i == 0);

    const float* ab = trans + (size_t)b * 903;
    const int r0 = (2*i)*7, r1 = (2*i+1)*7, r2 = (2*i+2)*7;

    // Linear-space params (exp hoisted to init).
    const float tmm0 = exp2_hw(ab[r0+0]*LOG2E);
    const float tim0 = exp2_hw(ab[r0+3]*LOG2E);
    const float tdm0 = exp2_hw(ab[r0+5]*LOG2E);
    const float tmd0 = exp2_hw(ab[r0+2]*LOG2E);
    const float tdd0 = exp2_hw(ab[r0+6]*LOG2E);
    const float tmm1 = exp2_hw(ab[r1+0]*LOG2E);
    const float tim1 = exp2_hw(ab[r1+3]*LOG2E);
    const float tdm1 = exp2_hw(ab[r1+5]*LOG2E);
    const float tmd1 = exp2_hw(ab[r1+2]*LOG2E);
    const float tdd1 = exp2_hw(ab[r1+6]*LOG2E);
    const float tmi1 = 0.25f*exp2_hw(ab[r1+1]*LOG2E);
    const float tii1 = 0.25f*exp2_hw(ab[r1+4]*LOG2E);
    const float tmi2 = 0.25f*exp2_hw(ab[r2+1]*LOG2E);
    const float tii2 = 0.25f*exp2_hw(ab[r2+4]*LOG2E);
    const float q1g  = 0.25f*exp2_hw(ab[1]*LOG2E);   // fI0[1]
    const float gg   = 0.25f*exp2_hw(ab[4]*LOG2E);   // fI0 geometric link
    const float tKmm = exp2_hw(ab[128*7+0]*LOG2E);
    const float tKim = exp2_hw(ab[128*7+3]*LOG2E);
    const float tKdm = exp2_hw(ab[128*7+5]*LOG2E);

    const float4* eb = (const float4*)(emis + (size_t)b*512);
    float4 el1 = eb[2*i], el2 = eb[2*i+1];
    el1.x=exp2_hw(el1.x*LOG2E); el1.y=exp2_hw(el1.y*LOG2E);
    el1.z=exp2_hw(el1.z*LOG2E); el1.w=exp2_hw(el1.w*LOG2E);
    el2.x=exp2_hw(el2.x*LOG2E); el2.y=exp2_hw(el2.y*LOG2E);
    el2.z=exp2_hw(el2.z*LOG2E); el2.w=exp2_hw(el2.w*LOG2E);

    const int4 ts = ((const int4*)(tokens + (size_t)b*256))[i];

    // Col-0 delete chain, closed form: log2 fD[k][0] = lmd(row0) + sum ldd(rows 1..k-1).
    const float ldd0 = ab[r0+6]*LOG2E;   // row 2i D2D (log2)
    const float ldd1 = ab[r1+6]*LOG2E;   // row 2i+1
    const float lmd0b = ab[2]*LOG2E;     // row 0 M2D (uniform scalar)
    float incl = (lane0 ? 0.0f : ldd0) + ldd1;
    #pragma unroll
    for (int d = 1; d < 64; d <<= 1) {
        float t = __shfl_up(incl, d);
        if (i >= d) incl += t;
    }
    float exPre = __shfl_up(incl, 1);
    if (lane0) exPre = 0.0f;             // rows 1..2i-1
    const float g1 = lmd0b + exPre + (lane0 ? 0.0f : ldd0); // log2 fD[2i+1][0]
    const float g2 = g1 + ldd1;                             // log2 fD[2i+2][0]

    int E = (int)floorf(fmaxf(g1, g2));  // per-lane scale anchor
    float cMx = 0.0f, cMy = 0.0f, cIx = 0.0f, cIy = 0.0f;
    float cDx = exp2_hw(g1 - (float)E), cDy = exp2_hw(g2 - (float)E);
    float emM = 0.0f, emI = 0.0f, emD = 0.0f;   // mid exports (col c, row k2)
    float pM = 0.0f, pI = 0.0f, pD = 0.0f; int pE = 0; // saved end (col c-1), raw
    float u = 0.0f; int EI0 = 0;                // fI0[2s-2], scale 2^EI0 (uniform)
    int symq = 0;                               // symbol-pair delay register
    const float m00 = ldx(1.0f, -E);            // fM[0][0] in lane0's scale

    // 96 groups x 2 steps: s = 1..192 (lane 63's last active step is 191).
    #pragma unroll 1
    for (int n = 0; n < 96; ++n) {
        const int sel = n & 63;   // group n consumes tokens 4n..4n+3 (n>63: unused)
        const int t0 = __builtin_amdgcn_readlane(ts.x, sel);
        const int t1 = __builtin_amdgcn_readlane(ts.y, sel);
        const int t2 = __builtin_amdgcn_readlane(ts.z, sel);
        const int t3 = __builtin_amdgcn_readlane(ts.w, sel);
        STEP(t0 | (t1 << 2), n == 0, 2*n);      // s = 2n+1
        STEP(t2 | (t3 << 2), false,  2*n + 1);  // s = 2n+2
        RESCALE;
    }

    // lane 63 holds k=127,128 @ col 256; y = k=128.
    const float fin = fmaf(tKdm, cDy, fmaf(tKim, cIy, tKmm*cMy));
    if (i == 63) nll_out[b] = -(log2_hw(fin) + (float)E)*LN2;
}

__global__ __launch_bounds__(256) void phmm_finish(const float* __restrict__ nll,
                                                   const float* __restrict__ mus,
                                                   const float* __restrict__ logvars,
                                                   float* __restrict__ out)
{
    const int tid = threadIdx.x;
    float acc = 0.0f;
    for (int idx = tid; idx < 512; idx += 256) acc += nll[idx];
    for (int idx = tid; idx < 8192; idx += 256) {
        const float mu = mus[idx], lv = logvars[idx];
        acc -= 0.5f * (1.0f + lv - mu * mu - exp2_hw(lv * LOG2E));
    }
    #pragma unroll
    for (int off = 32; off >= 1; off >>= 1) acc += __shfl_down(acc, off);
    __shared__ float red[4];
    if ((tid & 63) == 0) red[tid >> 6] = acc;
    __syncthreads();
    if (tid == 0) out[0] = (red[0] + red[1] + red[2] + red[3]) * (1.0f / 512.0f);
}

extern "C" void kernel_launch(void* const* d_in, const int* in_sizes, int n_in,
                              void* d_out, int out_size, void* d_ws, size_t ws_size,
                              hipStream_t stream)
{
    const int*   tokens  = (const int*)d_in[0];   // (512, 256) int32
    const float* trans   = (const float*)d_in[1]; // (512, 129, 7) f32
    const float* emis    = (const float*)d_in[2]; // (512, 128, 4) f32
    const float* mus     = (const float*)d_in[3]; // (512, 16) f32
    const float* logvars = (const float*)d_in[4]; // (512, 16) f32
    float* nll = (float*)d_ws;                    // 512 floats scratch

    phmm_fwd<<<dim3(512), dim3(64), 0, stream>>>(tokens, trans, emis, nll);
    phmm_finish<<<dim3(1), dim3(256), 0, stream>>>(nll, mus, logvars, (float*)d_out);
}

// Round 12
// 52.357 us; speedup vs baseline: 1.6063x; 1.0014x over previous
//
#include <hip/hip_runtime.h>

// Profile-HMM forward + KLD, MI355X.
// v11 = v10 (linear-space, 2 columns/step, E on own DPP channel) with the
// step/rescale LAMBDAS replaced by MACROS. v10's lambdas captured ~30 locals
// by reference; clang failed SROA -> alloca -> AMDGPU PromoteAlloca put the
// whole DP state in LDS (LDS_Block_Size=2048, 1.7M bank conflicts, VGPR=32).
// Macros over plain locals keep state in VGPRs (v8 idiom: LDS=0).

typedef float v2f __attribute__((ext_vector_type(2)));

constexpr float LOG2E = 1.4426950408889634f;
constexpr float LN2   = 0.6931471805599453f;

__device__ __forceinline__ float exp2_hw(float x){ return __builtin_amdgcn_exp2f(x); }
__device__ __forceinline__ float log2_hw(float x){ return __builtin_amdgcn_logf(x); }
__device__ __forceinline__ float ldx(float x,int e){ return __builtin_amdgcn_ldexpf(x,e); }
__device__ __forceinline__ int   fxe(float x){ return __builtin_amdgcn_frexp_expf(x); }
// DPP wave_shr:1 — lane i gets lane i-1's src; lane 0 gets old_.
__device__ __forceinline__ int   dppi(int o,int s){ return __builtin_amdgcn_update_dpp(o,s,0x138,0xF,0xF,false); }
__device__ __forceinline__ float dppf(float o,float s){ return __int_as_float(dppi(__float_as_int(o),__float_as_int(s))); }

// One 2-col step: cols c = 2*SM1+1-2i, c+1. All operands are named locals.
#define STEP(FRESH, ISS1, SM1) do {                                            \
    const float qmM = dppf(0.0f, emM);   /* neighbor k0 @ col c   */           \
    const float qmI = dppf(0.0f, emI);                                         \
    const float qmD = dppf(0.0f, emD);                                         \
    const float qeM = dppf(0.0f, cMy);   /* neighbor k0 @ col c+1 */           \
    const float qeI = dppf(0.0f, cIy);                                         \
    const float qeD = dppf(0.0f, cDy);                                         \
    const int   qE  = dppi(0, E);        /* neighbor CURRENT scale */          \
    const int qsym  = dppi((FRESH), symq);                                     \
    const float sq = ldx(1.0f, qE - E);                                        \
    const float sp = ldx(1.0f, pE - E);                                        \
    const float v = (ISS1) ? q1g : gg * u;  /* fI0[2s-1] */                    \
    float mM = qmM * sq, mI = qmI * sq, mD = qmD * sq;                         \
    float eM_ = qeM * sq, eD_ = qeD * sq;                                      \
    float PM = pM * sp, PI = pI * sp, PD = pD * sp;                            \
    if (lane0) {                          /* virtual row 0 boundary */         \
        PM = (ISS1) ? m00 : 0.0f;                                              \
        PI = ldx(u, EI0 - E);                                                  \
        PD = 0.0f;                                                             \
        mM = 0.0f; mD = 0.0f;                                                  \
        mI = ldx(v, EI0 - E);                                                  \
        eM_ = 0.0f; eD_ = 0.0f;                                                \
    }                                                                          \
    const int sa = qsym & 3, sb = (qsym >> 2) & 3;                             \
    const float e1c = (sa & 2) ? ((sa & 1) ? el1.w : el1.z) : ((sa & 1) ? el1.y : el1.x); \
    const float e2c = (sa & 2) ? ((sa & 1) ? el2.w : el2.z) : ((sa & 1) ? el2.y : el2.x); \
    const float e1d = (sb & 2) ? ((sb & 1) ? el1.w : el1.z) : ((sb & 1) ? el1.y : el1.x); \
    const float e2d = (sb & 2) ? ((sb & 1) ? el2.w : el2.z) : ((sb & 1) ? el2.y : el2.x); \
    /* col c (from state @ c-1) */                                             \
    const float nM1 = e1c * fmaf(tdm0, PD,  fmaf(tim0, PI,  tmm0 * PM));       \
    const float nM2 = e2c * fmaf(tdm1, cDx, fmaf(tim1, cIx, tmm1 * cMx));      \
    const float nI1 = fmaf(tmi1, cMx, tii1 * cIx);                             \
    const float nI2 = fmaf(tmi2, cMy, tii2 * cIy);                             \
    const float nD1 = fmaf(tmd0, mM, tdd0 * mD);                               \
    const float nD2 = fmaf(tmd1, nM1, tdd1 * nD1);                             \
    /* col c+1 */                                                              \
    const float nM1b = e1d * fmaf(tdm0, mD,  fmaf(tim0, mI,  tmm0 * mM));      \
    const float nM2b = e2d * fmaf(tdm1, nD1, fmaf(tim1, nI1, tmm1 * nM1));     \
    const float nI1b = fmaf(tmi1, nM1, tii1 * nI1);                            \
    const float nI2b = fmaf(tmi2, nM2, tii2 * nI2);                            \
    const float nD1b = fmaf(tmd0, eM_, tdd0 * eD_);                            \
    const float nD2b = fmaf(tmd1, nM1b, tdd1 * nD1b);                          \
    emM = nM2; emI = nI2; emD = nD2;      /* mid exports (unmasked) */         \
    const bool act = ((unsigned)((SM1) - i)) < 128u;                           \
    cMx = act ? nM1b : cMx;  cMy = act ? nM2b : cMy;                           \
    cIx = act ? nI1b : cIx;  cIy = act ? nI2b : cIy;                           \
    cDx = act ? nD1b : cDx;  cDy = act ? nD2b : cDy;                           \
    pM = qeM; pI = qeI; pD = qeD; pE = qE;                                     \
    symq = qsym;                                                               \
    u = gg * v;                            /* fI0[2s] */                       \
} while (0)

#define RESCALE do {                                                           \
    const float anc = fmaxf(fmaxf(fmaxf(cMx, cMy), fmaxf(cIx, cIy)),           \
                            fmaxf(cDx, cDy));                                  \
    const int e = fxe(anc);                                                    \
    E += e;                                                                    \
    const float sE = ldx(1.0f, -e);                                            \
    cMx *= sE; cMy *= sE; cIx *= sE; cIy *= sE; cDx *= sE; cDy *= sE;          \
    emM *= sE; emI *= sE; emD *= sE;                                           \
    const int eI = fxe(u); EI0 += eI; u = ldx(u, -eI);                         \
} while (0)

// transitions: (B, 129, 7)  M2M=0 M2I=1 M2D=2 I2M=3 I2I=4 D2M=5 D2D=6
// emissions:   (B, 128, 4);  tokens: (B, 256) int32 in [0,4)
__global__ __launch_bounds__(64) void phmm_fwd(const int* __restrict__ tokens,
                                               const float* __restrict__ trans,
                                               const float* __restrict__ emis,
                                               float* __restrict__ nll_out)
{
    const int b = blockIdx.x;
    const int i = threadIdx.x;
    const bool lane0 = (i == 0);

    const float* ab = trans + (size_t)b * 903;
    const int r0 = (2*i)*7, r1 = (2*i+1)*7, r2 = (2*i+2)*7;

    // Linear-space params (exp hoisted to init).
    const float tmm0 = exp2_hw(ab[r0+0]*LOG2E);
    const float tim0 = exp2_hw(ab[r0+3]*LOG2E);
    const float tdm0 = exp2_hw(ab[r0+5]*LOG2E);
    const float tmd0 = exp2_hw(ab[r0+2]*LOG2E);
    const float tdd0 = exp2_hw(ab[r0+6]*LOG2E);
    const float tmm1 = exp2_hw(ab[r1+0]*LOG2E);
    const float tim1 = exp2_hw(ab[r1+3]*LOG2E);
    const float tdm1 = exp2_hw(ab[r1+5]*LOG2E);
    const float tmd1 = exp2_hw(ab[r1+2]*LOG2E);
    const float tdd1 = exp2_hw(ab[r1+6]*LOG2E);
    const float tmi1 = 0.25f*exp2_hw(ab[r1+1]*LOG2E);
    const float tii1 = 0.25f*exp2_hw(ab[r1+4]*LOG2E);
    const float tmi2 = 0.25f*exp2_hw(ab[r2+1]*LOG2E);
    const float tii2 = 0.25f*exp2_hw(ab[r2+4]*LOG2E);
    const float q1g  = 0.25f*exp2_hw(ab[1]*LOG2E);   // fI0[1]
    const float gg   = 0.25f*exp2_hw(ab[4]*LOG2E);   // fI0 geometric link
    const float tKmm = exp2_hw(ab[128*7+0]*LOG2E);
    const float tKim = exp2_hw(ab[128*7+3]*LOG2E);
    const float tKdm = exp2_hw(ab[128*7+5]*LOG2E);

    const float4* eb = (const float4*)(emis + (size_t)b*512);
    float4 el1 = eb[2*i], el2 = eb[2*i+1];
    el1.x=exp2_hw(el1.x*LOG2E); el1.y=exp2_hw(el1.y*LOG2E);
    el1.z=exp2_hw(el1.z*LOG2E); el1.w=exp2_hw(el1.w*LOG2E);
    el2.x=exp2_hw(el2.x*LOG2E); el2.y=exp2_hw(el2.y*LOG2E);
    el2.z=exp2_hw(el2.z*LOG2E); el2.w=exp2_hw(el2.w*LOG2E);

    const int4 ts = ((const int4*)(tokens + (size_t)b*256))[i];

    // Col-0 delete chain, closed form: log2 fD[k][0] = lmd(row0) + sum ldd(rows 1..k-1).
    const float ldd0 = ab[r0+6]*LOG2E;   // row 2i D2D (log2)
    const float ldd1 = ab[r1+6]*LOG2E;   // row 2i+1
    const float lmd0b = ab[2]*LOG2E;     // row 0 M2D (uniform scalar)
    float incl = (lane0 ? 0.0f : ldd0) + ldd1;
    #pragma unroll
    for (int d = 1; d < 64; d <<= 1) {
        float t = __shfl_up(incl, d);
        if (i >= d) incl += t;
    }
    float exPre = __shfl_up(incl, 1);
    if (lane0) exPre = 0.0f;             // rows 1..2i-1
    const float g1 = lmd0b + exPre + (lane0 ? 0.0f : ldd0); // log2 fD[2i+1][0]
    const float g2 = g1 + ldd1;                             // log2 fD[2i+2][0]

    int E = (int)floorf(fmaxf(g1, g2));  // per-lane scale anchor
    float cMx = 0.0f, cMy = 0.0f, cIx = 0.0f, cIy = 0.0f;
    float cDx = exp2_hw(g1 - (float)E), cDy = exp2_hw(g2 - (float)E);
    float emM = 0.0f, emI = 0.0f, emD = 0.0f;   // mid exports (col c, row k2)
    float pM = 0.0f, pI = 0.0f, pD = 0.0f; int pE = 0; // saved end (col c-1), raw
    float u = 0.0f; int EI0 = 0;                // fI0[2s-2], scale 2^EI0 (uniform)
    int symq = 0;                               // symbol-pair delay register
    const float m00 = ldx(1.0f, -E);            // fM[0][0] in lane0's scale

    // 96 groups x 2 steps: s = 1..192 (lane 63's last active step is 191).
    #pragma unroll 1
    for (int n = 0; n < 96; ++n) {
        const int sel = n & 63;   // group n consumes tokens 4n..4n+3 (n>63: unused)
        const int t0 = __builtin_amdgcn_readlane(ts.x, sel);
        const int t1 = __builtin_amdgcn_readlane(ts.y, sel);
        const int t2 = __builtin_amdgcn_readlane(ts.z, sel);
        const int t3 = __builtin_amdgcn_readlane(ts.w, sel);
        STEP(t0 | (t1 << 2), n == 0, 2*n);      // s = 2n+1
        STEP(t2 | (t3 << 2), false,  2*n + 1);  // s = 2n+2
        RESCALE;
    }

    // lane 63 holds k=127,128 @ col 256; y = k=128.
    const float fin = fmaf(tKdm, cDy, fmaf(tKim, cIy, tKmm*cMy));
    if (i == 63) nll_out[b] = -(log2_hw(fin) + (float)E)*LN2;
}

__global__ __launch_bounds__(256) void phmm_finish(const float* __restrict__ nll,
                                                   const float* __restrict__ mus,
                                                   const float* __restrict__ logvars,
                                                   float* __restrict__ out)
{
    const int tid = threadIdx.x;
    float acc = 0.0f;
    for (int idx = tid; idx < 512; idx += 256) acc += nll[idx];
    for (int idx = tid; idx < 8192; idx += 256) {
        const float mu = mus[idx], lv = logvars[idx];
        acc -= 0.5f * (1.0f + lv - mu * mu - exp2_hw(lv * LOG2E));
    }
    #pragma unroll
    for (int off = 32; off >= 1; off >>= 1) acc += __shfl_down(acc, off);
    __shared__ float red[4];
    if ((tid & 63) == 0) red[tid >> 6] = acc;
    __syncthreads();
    if (tid == 0) out[0] = (red[0] + red[1] + red[2] + red[3]) * (1.0f / 512.0f);
}

extern "C" void kernel_launch(void* const* d_in, const int* in_sizes, int n_in,
                              void* d_out, int out_size, void* d_ws, size_t ws_size,
                              hipStream_t stream)
{
    const int*   tokens  = (const int*)d_in[0];   // (512, 256) int32
    const float* trans   = (const float*)d_in[1]; // (512, 129, 7) f32
    const float* emis    = (const float*)d_in[2]; // (512, 128, 4) f32
    const float* mus     = (const float*)d_in[3]; // (512, 16) f32
    const float* logvars = (const float*)d_in[4]; // (512, 16) f32
    float* nll = (float*)d_ws;                    // 512 floats scratch

    phmm_fwd<<<dim3(512), dim3(64), 0, stream>>>(tokens, trans, emis, nll);
    phmm_finish<<<dim3(1), dim3(256), 0, stream>>>(nll, mus, logvars, (float*)d_out);
}

// Round 13
// 51.008 us; speedup vs baseline: 1.6487x; 1.0264x over previous
//
#include <hip/hip_runtime.h>

// Profile-HMM forward + KLD, MI355X.
// v12 = v11 (linear-space, 2 cols/step, macros, state in VGPRs) with the
// scheduler unshackled: __launch_bounds__(64, 1) sets waves-per-EU=1 so the
// pre-RA scheduler stops minimizing register pressure (v11: VGPR=32, ILP~1,
// ~7 cyc/inst at VALUBusy 30%) and schedules for latency with up to 512
// VGPRs; plus unroll-2 on the group loop for cross-step interleave.
// We structurally run 1 wave/SIMD (512 waves on 1024 SIMDs) - occupancy is
// free, register pressure is free.

typedef float v2f __attribute__((ext_vector_type(2)));

constexpr float LOG2E = 1.4426950408889634f;
constexpr float LN2   = 0.6931471805599453f;

__device__ __forceinline__ float exp2_hw(float x){ return __builtin_amdgcn_exp2f(x); }
__device__ __forceinline__ float log2_hw(float x){ return __builtin_amdgcn_logf(x); }
__device__ __forceinline__ float ldx(float x,int e){ return __builtin_amdgcn_ldexpf(x,e); }
__device__ __forceinline__ int   fxe(float x){ return __builtin_amdgcn_frexp_expf(x); }
// DPP wave_shr:1 — lane i gets lane i-1's src; lane 0 gets old_.
__device__ __forceinline__ int   dppi(int o,int s){ return __builtin_amdgcn_update_dpp(o,s,0x138,0xF,0xF,false); }
__device__ __forceinline__ float dppf(float o,float s){ return __int_as_float(dppi(__float_as_int(o),__float_as_int(s))); }

// One 2-col step: cols c = 2*SM1+1-2i, c+1. All operands are named locals.
#define STEP(FRESH, ISS1, SM1) do {                                            \
    const float qmM = dppf(0.0f, emM);   /* neighbor k0 @ col c   */           \
    const float qmI = dppf(0.0f, emI);                                         \
    const float qmD = dppf(0.0f, emD);                                         \
    const float qeM = dppf(0.0f, cMy);   /* neighbor k0 @ col c+1 */           \
    const float qeI = dppf(0.0f, cIy);                                         \
    const float qeD = dppf(0.0f, cDy);                                         \
    const int   qE  = dppi(0, E);        /* neighbor CURRENT scale */          \
    const int qsym  = dppi((FRESH), symq);                                     \
    const float sq = ldx(1.0f, qE - E);                                        \
    const float sp = ldx(1.0f, pE - E);                                        \
    const float v = (ISS1) ? q1g : gg * u;  /* fI0[2s-1] */                    \
    float mM = qmM * sq, mI = qmI * sq, mD = qmD * sq;                         \
    float eM_ = qeM * sq, eD_ = qeD * sq;                                      \
    float PM = pM * sp, PI = pI * sp, PD = pD * sp;                            \
    if (lane0) {                          /* virtual row 0 boundary */         \
        PM = (ISS1) ? m00 : 0.0f;                                              \
        PI = ldx(u, EI0 - E);                                                  \
        PD = 0.0f;                                                             \
        mM = 0.0f; mD = 0.0f;                                                  \
        mI = ldx(v, EI0 - E);                                                  \
        eM_ = 0.0f; eD_ = 0.0f;                                                \
    }                                                                          \
    const int sa = qsym & 3, sb = (qsym >> 2) & 3;                             \
    const float e1c = (sa & 2) ? ((sa & 1) ? el1.w : el1.z) : ((sa & 1) ? el1.y : el1.x); \
    const float e2c = (sa & 2) ? ((sa & 1) ? el2.w : el2.z) : ((sa & 1) ? el2.y : el2.x); \
    const float e1d = (sb & 2) ? ((sb & 1) ? el1.w : el1.z) : ((sb & 1) ? el1.y : el1.x); \
    const float e2d = (sb & 2) ? ((sb & 1) ? el2.w : el2.z) : ((sb & 1) ? el2.y : el2.x); \
    /* col c (from state @ c-1) */                                             \
    const float nM1 = e1c * fmaf(tdm0, PD,  fmaf(tim0, PI,  tmm0 * PM));       \
    const float nM2 = e2c * fmaf(tdm1, cDx, fmaf(tim1, cIx, tmm1 * cMx));      \
    const float nI1 = fmaf(tmi1, cMx, tii1 * cIx);                             \
    const float nI2 = fmaf(tmi2, cMy, tii2 * cIy);                             \
    const float nD1 = fmaf(tmd0, mM, tdd0 * mD);                               \
    const float nD2 = fmaf(tmd1, nM1, tdd1 * nD1);                             \
    /* col c+1 */                                                              \
    const float nM1b = e1d * fmaf(tdm0, mD,  fmaf(tim0, mI,  tmm0 * mM));      \
    const float nM2b = e2d * fmaf(tdm1, nD1, fmaf(tim1, nI1, tmm1 * nM1));     \
    const float nI1b = fmaf(tmi1, nM1, tii1 * nI1);                            \
    const float nI2b = fmaf(tmi2, nM2, tii2 * nI2);                            \
    const float nD1b = fmaf(tmd0, eM_, tdd0 * eD_);                            \
    const float nD2b = fmaf(tmd1, nM1b, tdd1 * nD1b);                          \
    emM = nM2; emI = nI2; emD = nD2;      /* mid exports (unmasked) */         \
    const bool act = ((unsigned)((SM1) - i)) < 128u;                           \
    cMx = act ? nM1b : cMx;  cMy = act ? nM2b : cMy;                           \
    cIx = act ? nI1b : cIx;  cIy = act ? nI2b : cIy;                           \
    cDx = act ? nD1b : cDx;  cDy = act ? nD2b : cDy;                           \
    pM = qeM; pI = qeI; pD = qeD; pE = qE;                                     \
    symq = qsym;                                                               \
    u = gg * v;                            /* fI0[2s] */                       \
} while (0)

#define RESCALE do {                                                           \
    const float anc = fmaxf(fmaxf(fmaxf(cMx, cMy), fmaxf(cIx, cIy)),           \
                            fmaxf(cDx, cDy));                                  \
    const int e = fxe(anc);                                                    \
    E += e;                                                                    \
    const float sE = ldx(1.0f, -e);                                            \
    cMx *= sE; cMy *= sE; cIx *= sE; cIy *= sE; cDx *= sE; cDy *= sE;          \
    emM *= sE; emI *= sE; emD *= sE;                                           \
    const int eI = fxe(u); EI0 += eI; u = ldx(u, -eI);                         \
} while (0)

// transitions: (B, 129, 7)  M2M=0 M2I=1 M2D=2 I2M=3 I2I=4 D2M=5 D2D=6
// emissions:   (B, 128, 4);  tokens: (B, 256) int32 in [0,4)
__global__ __launch_bounds__(64, 1) void phmm_fwd(const int* __restrict__ tokens,
                                                  const float* __restrict__ trans,
                                                  const float* __restrict__ emis,
                                                  float* __restrict__ nll_out)
{
    const int b = blockIdx.x;
    const int i = threadIdx.x;
    const bool lane0 = (i == 0);

    const float* ab = trans + (size_t)b * 903;
    const int r0 = (2*i)*7, r1 = (2*i+1)*7, r2 = (2*i+2)*7;

    // Linear-space params (exp hoisted to init).
    const float tmm0 = exp2_hw(ab[r0+0]*LOG2E);
    const float tim0 = exp2_hw(ab[r0+3]*LOG2E);
    const float tdm0 = exp2_hw(ab[r0+5]*LOG2E);
    const float tmd0 = exp2_hw(ab[r0+2]*LOG2E);
    const float tdd0 = exp2_hw(ab[r0+6]*LOG2E);
    const float tmm1 = exp2_hw(ab[r1+0]*LOG2E);
    const float tim1 = exp2_hw(ab[r1+3]*LOG2E);
    const float tdm1 = exp2_hw(ab[r1+5]*LOG2E);
    const float tmd1 = exp2_hw(ab[r1+2]*LOG2E);
    const float tdd1 = exp2_hw(ab[r1+6]*LOG2E);
    const float tmi1 = 0.25f*exp2_hw(ab[r1+1]*LOG2E);
    const float tii1 = 0.25f*exp2_hw(ab[r1+4]*LOG2E);
    const float tmi2 = 0.25f*exp2_hw(ab[r2+1]*LOG2E);
    const float tii2 = 0.25f*exp2_hw(ab[r2+4]*LOG2E);
    const float q1g  = 0.25f*exp2_hw(ab[1]*LOG2E);   // fI0[1]
    const float gg   = 0.25f*exp2_hw(ab[4]*LOG2E);   // fI0 geometric link
    const float tKmm = exp2_hw(ab[128*7+0]*LOG2E);
    const float tKim = exp2_hw(ab[128*7+3]*LOG2E);
    const float tKdm = exp2_hw(ab[128*7+5]*LOG2E);

    const float4* eb = (const float4*)(emis + (size_t)b*512);
    float4 el1 = eb[2*i], el2 = eb[2*i+1];
    el1.x=exp2_hw(el1.x*LOG2E); el1.y=exp2_hw(el1.y*LOG2E);
    el1.z=exp2_hw(el1.z*LOG2E); el1.w=exp2_hw(el1.w*LOG2E);
    el2.x=exp2_hw(el2.x*LOG2E); el2.y=exp2_hw(el2.y*LOG2E);
    el2.z=exp2_hw(el2.z*LOG2E); el2.w=exp2_hw(el2.w*LOG2E);

    const int4 ts = ((const int4*)(tokens + (size_t)b*256))[i];

    // Col-0 delete chain, closed form: log2 fD[k][0] = lmd(row0) + sum ldd(rows 1..k-1).
    const float ldd0 = ab[r0+6]*LOG2E;   // row 2i D2D (log2)
    const float ldd1 = ab[r1+6]*LOG2E;   // row 2i+1
    const float lmd0b = ab[2]*LOG2E;     // row 0 M2D (uniform scalar)
    float incl = (lane0 ? 0.0f : ldd0) + ldd1;
    #pragma unroll
    for (int d = 1; d < 64; d <<= 1) {
        float t = __shfl_up(incl, d);
        if (i >= d) incl += t;
    }
    float exPre = __shfl_up(incl, 1);
    if (lane0) exPre = 0.0f;             // rows 1..2i-1
    const float g1 = lmd0b + exPre + (lane0 ? 0.0f : ldd0); // log2 fD[2i+1][0]
    const float g2 = g1 + ldd1;                             // log2 fD[2i+2][0]

    int E = (int)floorf(fmaxf(g1, g2));  // per-lane scale anchor
    float cMx = 0.0f, cMy = 0.0f, cIx = 0.0f, cIy = 0.0f;
    float cDx = exp2_hw(g1 - (float)E), cDy = exp2_hw(g2 - (float)E);
    float emM = 0.0f, emI = 0.0f, emD = 0.0f;   // mid exports (col c, row k2)
    float pM = 0.0f, pI = 0.0f, pD = 0.0f; int pE = 0; // saved end (col c-1), raw
    float u = 0.0f; int EI0 = 0;                // fI0[2s-2], scale 2^EI0 (uniform)
    int symq = 0;                               // symbol-pair delay register
    const float m00 = ldx(1.0f, -E);            // fM[0][0] in lane0's scale

    // 96 groups x 2 steps: s = 1..192 (lane 63's last active step is 191).
    #pragma unroll 2
    for (int n = 0; n < 96; ++n) {
        const int sel = n & 63;   // group n consumes tokens 4n..4n+3 (n>63: unused)
        const int t0 = __builtin_amdgcn_readlane(ts.x, sel);
        const int t1 = __builtin_amdgcn_readlane(ts.y, sel);
        const int t2 = __builtin_amdgcn_readlane(ts.z, sel);
        const int t3 = __builtin_amdgcn_readlane(ts.w, sel);
        STEP(t0 | (t1 << 2), n == 0, 2*n);      // s = 2n+1
        STEP(t2 | (t3 << 2), false,  2*n + 1);  // s = 2n+2
        RESCALE;
    }

    // lane 63 holds k=127,128 @ col 256; y = k=128.
    const float fin = fmaf(tKdm, cDy, fmaf(tKim, cIy, tKmm*cMy));
    if (i == 63) nll_out[b] = -(log2_hw(fin) + (float)E)*LN2;
}

__global__ __launch_bounds__(256) void phmm_finish(const float* __restrict__ nll,
                                                   const float* __restrict__ mus,
                                                   const float* __restrict__ logvars,
                                                   float* __restrict__ out)
{
    const int tid = threadIdx.x;
    float acc = 0.0f;
    for (int idx = tid; idx < 512; idx += 256) acc += nll[idx];
    for (int idx = tid; idx < 8192; idx += 256) {
        const float mu = mus[idx], lv = logvars[idx];
        acc -= 0.5f * (1.0f + lv - mu * mu - exp2_hw(lv * LOG2E));
    }
    #pragma unroll
    for (int off = 32; off >= 1; off >>= 1) acc += __shfl_down(acc, off);
    __shared__ float red[4];
    if ((tid & 63) == 0) red[tid >> 6] = acc;
    __syncthreads();
    if (tid == 0) out[0] = (red[0] + red[1] + red[2] + red[3]) * (1.0f / 512.0f);
}

extern "C" void kernel_launch(void* const* d_in, const int* in_sizes, int n_in,
                              void* d_out, int out_size, void* d_ws, size_t ws_size,
                              hipStream_t stream)
{
    const int*   tokens  = (const int*)d_in[0];   // (512, 256) int32
    const float* trans   = (const float*)d_in[1]; // (512, 129, 7) f32
    const float* emis    = (const float*)d_in[2]; // (512, 128, 4) f32
    const float* mus     = (const float*)d_in[3]; // (512, 16) f32
    const float* logvars = (const float*)d_in[4]; // (512, 16) f32
    float* nll = (float*)d_ws;                    // 512 floats scratch

    phmm_fwd<<<dim3(512), dim3(64), 0, stream>>>(tokens, trans, emis, nll);
    phmm_finish<<<dim3(1), dim3(256), 0, stream>>>(nll, mus, logvars, (float*)d_out);
}

// Round 15
// 42.684 us; speedup vs baseline: 1.9703x; 1.1950x over previous
//
#include <hip/hip_runtime.h>

// Profile-HMM forward + KLD, MI355X.
// v14 = v13 with the NaN fix: the neighbor-scale DPP uses old=E (lane 0 reads
// its OWN exponent -> dE=0 -> sq=1.0 exactly). v13's lane0 got qE=0 while its
// real E drifts to ~-500, making sq=2^500=inf and 0*inf=NaN. All other lane-0
// boundary inputs are 0 via DPP old=0, and 0 * finite = 0 as required.
// Diet vs v12: no lane0 fixup branch; fill/steady/drain loop split (steady
// steps are mask-free, drain has no readlanes); RESCALE every 4 steps.

constexpr float LOG2E = 1.4426950408889634f;
constexpr float LN2   = 0.6931471805599453f;

__device__ __forceinline__ float exp2_hw(float x){ return __builtin_amdgcn_exp2f(x); }
__device__ __forceinline__ float log2_hw(float x){ return __builtin_amdgcn_logf(x); }
__device__ __forceinline__ float ldx(float x,int e){ return __builtin_amdgcn_ldexpf(x,e); }
__device__ __forceinline__ int   fxe(float x){ return __builtin_amdgcn_frexp_expf(x); }
// DPP wave_shr:1 — lane i gets lane i-1's src; lane 0 gets old_.
__device__ __forceinline__ int   dppi(int o,int s){ return __builtin_amdgcn_update_dpp(o,s,0x138,0xF,0xF,false); }
__device__ __forceinline__ float dppf(float o,float s){ return __int_as_float(dppi(__float_as_int(o),__float_as_int(s))); }

// One 2-col step: cols c = 2*(SM1+1)-1-2i, c+1.
#define STEP(FRESH, ISS1, MASKED, SM1) do {                                    \
    /* ---- phase 0: all cross-lane reads (independent) ---- */                \
    const float qmM = dppf(0.0f, emM);   /* neighbor k0 @ col c   */           \
    const float qmI = dppf(0.0f, emI);                                         \
    const float qmD = dppf(0.0f, emD);                                         \
    const float qeM = dppf(0.0f, cMy);   /* neighbor k0 @ col c+1 */           \
    const float qeI = dppf(0.0f, cIy);                                         \
    const float qeD = dppf(0.0f, cDy);                                         \
    const int   qE  = dppi(E, E);        /* lane0: own E -> sq = 1.0 exact */  \
    const int qsym  = dppi((FRESH), symq);                                     \
    /* ---- phase 1: prev-state-only chains + scale factors ---- */            \
    const float v   = (ISS1) ? q1g : gg * u;    /* fI0[2s-1] */                \
    const float nI1 = fmaf(tmi1, cMx, tii1 * cIx);                             \
    const float nI2 = fmaf(tmi2, cMy, tii2 * cIy);                             \
    const float sq  = ldx(1.0f, qE - E);                                       \
    const float sp  = ldx(1.0f, pE - E);                                       \
    const float tPI = ldx(u, EI0 - E);   /* lane0 fI0 injections */            \
    const float tmI = ldx(v, EI0 - E);                                         \
    /* ---- phase 2: scale conversions (independent muls) ---- */              \
    const float mM  = qmM * sq;          /* lane0: 0 * 1 = 0 */                \
    const float mD  = qmD * sq;                                                \
    const float eM_ = qeM * sq;                                                \
    const float eD_ = qeD * sq;                                                \
    const float PM  = pM * sp;           /* step1 lane0: 1*2^-E = fM[0][0] */  \
    const float PD  = pD * sp;                                                 \
    const float mI  = lane0 ? tmI : qmI * sq;                                  \
    const float PI  = lane0 ? tPI : pI * sp;                                   \
    /* ---- emission selects ---- */                                           \
    const bool ba = (qsym & 1) != 0, bb = (qsym & 2) != 0;                     \
    const bool bc = (qsym & 4) != 0, bd = (qsym & 8) != 0;                     \
    const float e1c = bb ? (ba ? el1.w : el1.z) : (ba ? el1.y : el1.x);        \
    const float e2c = bb ? (ba ? el2.w : el2.z) : (ba ? el2.y : el2.x);        \
    const float e1d = bd ? (bc ? el1.w : el1.z) : (bc ? el1.y : el1.x);        \
    const float e2d = bd ? (bc ? el2.w : el2.z) : (bc ? el2.y : el2.x);        \
    /* ---- col c ---- */                                                      \
    const float nM1 = e1c * fmaf(tdm0, PD,  fmaf(tim0, PI,  tmm0 * PM));       \
    const float nM2 = e2c * fmaf(tdm1, cDx, fmaf(tim1, cIx, tmm1 * cMx));      \
    const float nD1 = fmaf(tmd0, mM, tdd0 * mD);                               \
    const float nD2 = fmaf(tmd1, nM1, tdd1 * nD1);                             \
    /* ---- col c+1 ---- */                                                    \
    const float nM1b = e1d * fmaf(tdm0, mD,  fmaf(tim0, mI,  tmm0 * mM));      \
    const float nI1b = fmaf(tmi1, nM1, tii1 * nI1);                            \
    const float nI2b = fmaf(tmi2, nM2, tii2 * nI2);                            \
    const float nD1b = fmaf(tmd0, eM_, tdd0 * eD_);                            \
    const float nM2b = e2d * fmaf(tdm1, nD1, fmaf(tim1, nI1, tmm1 * nM1));     \
    const float nD2b = fmaf(tmd1, nM1b, tdd1 * nD1b);                          \
    /* ---- commit ---- */                                                     \
    emM = nM2; emI = nI2; emD = nD2;      /* mid exports (unmasked) */         \
    if (MASKED) {                                                              \
        const bool act = ((unsigned)((SM1) - i)) < 128u;                       \
        cMx = act ? nM1b : cMx;  cMy = act ? nM2b : cMy;                       \
        cIx = act ? nI1b : cIx;  cIy = act ? nI2b : cIy;                       \
        cDx = act ? nD1b : cDx;  cDy = act ? nD2b : cDy;                       \
    } else {                                                                   \
        cMx = nM1b; cMy = nM2b; cIx = nI1b; cIy = nI2b; cDx = nD1b; cDy = nD2b;\
    }                                                                          \
    pM = qeM; pI = qeI; pD = qeD; pE = qE;                                     \
    symq = qsym;                                                               \
    u = gg * v;                            /* fI0[2s] */                       \
} while (0)

#define RESCALE do {                                                           \
    const float anc = fmaxf(fmaxf(fmaxf(cMx, cMy), fmaxf(cIx, cIy)),           \
                            fmaxf(cDx, cDy));                                  \
    const int e = fxe(anc);                                                    \
    E += e;                                                                    \
    const float sE = ldx(1.0f, -e);                                            \
    cMx *= sE; cMy *= sE; cIx *= sE; cIy *= sE; cDx *= sE; cDy *= sE;          \
    emM *= sE; emI *= sE; emD *= sE;                                           \
    const int eI = fxe(u); EI0 += eI; u = ldx(u, -eI);                         \
} while (0)

// transitions: (B, 129, 7)  M2M=0 M2I=1 M2D=2 I2M=3 I2I=4 D2M=5 D2D=6
// emissions:   (B, 128, 4);  tokens: (B, 256) int32 in [0,4)
__global__ __launch_bounds__(64, 1) void phmm_fwd(const int* __restrict__ tokens,
                                                  const float* __restrict__ trans,
                                                  const float* __restrict__ emis,
                                                  float* __restrict__ nll_out)
{
    const int b = blockIdx.x;
    const int i = threadIdx.x;
    const bool lane0 = (i == 0);

    const float* ab = trans + (size_t)b * 903;
    const int r0 = (2*i)*7, r1 = (2*i+1)*7, r2 = (2*i+2)*7;

    // Linear-space params (exp hoisted to init).
    const float tmm0 = exp2_hw(ab[r0+0]*LOG2E);
    const float tim0 = exp2_hw(ab[r0+3]*LOG2E);
    const float tdm0 = exp2_hw(ab[r0+5]*LOG2E);
    const float tmd0 = exp2_hw(ab[r0+2]*LOG2E);
    const float tdd0 = exp2_hw(ab[r0+6]*LOG2E);
    const float tmm1 = exp2_hw(ab[r1+0]*LOG2E);
    const float tim1 = exp2_hw(ab[r1+3]*LOG2E);
    const float tdm1 = exp2_hw(ab[r1+5]*LOG2E);
    const float tmd1 = exp2_hw(ab[r1+2]*LOG2E);
    const float tdd1 = exp2_hw(ab[r1+6]*LOG2E);
    const float tmi1 = 0.25f*exp2_hw(ab[r1+1]*LOG2E);
    const float tii1 = 0.25f*exp2_hw(ab[r1+4]*LOG2E);
    const float tmi2 = 0.25f*exp2_hw(ab[r2+1]*LOG2E);
    const float tii2 = 0.25f*exp2_hw(ab[r2+4]*LOG2E);
    const float q1g  = 0.25f*exp2_hw(ab[1]*LOG2E);   // fI0[1]
    const float gg   = 0.25f*exp2_hw(ab[4]*LOG2E);   // fI0 geometric link
    const float tKmm = exp2_hw(ab[128*7+0]*LOG2E);
    const float tKim = exp2_hw(ab[128*7+3]*LOG2E);
    const float tKdm = exp2_hw(ab[128*7+5]*LOG2E);

    const float4* eb = (const float4*)(emis + (size_t)b*512);
    float4 el1 = eb[2*i], el2 = eb[2*i+1];
    el1.x=exp2_hw(el1.x*LOG2E); el1.y=exp2_hw(el1.y*LOG2E);
    el1.z=exp2_hw(el1.z*LOG2E); el1.w=exp2_hw(el1.w*LOG2E);
    el2.x=exp2_hw(el2.x*LOG2E); el2.y=exp2_hw(el2.y*LOG2E);
    el2.z=exp2_hw(el2.z*LOG2E); el2.w=exp2_hw(el2.w*LOG2E);

    const int4 ts = ((const int4*)(tokens + (size_t)b*256))[i];

    // Col-0 delete chain, closed form (log2 prefix scan).
    const float ldd0 = ab[r0+6]*LOG2E;
    const float ldd1 = ab[r1+6]*LOG2E;
    const float lmd0b = ab[2]*LOG2E;
    float incl = (lane0 ? 0.0f : ldd0) + ldd1;
    #pragma unroll
    for (int d = 1; d < 64; d <<= 1) {
        float t = __shfl_up(incl, d);
        if (i >= d) incl += t;
    }
    float exPre = __shfl_up(incl, 1);
    if (lane0) exPre = 0.0f;
    const float g1 = lmd0b + exPre + (lane0 ? 0.0f : ldd0); // log2 fD[2i+1][0]
    const float g2 = g1 + ldd1;                             // log2 fD[2i+2][0]

    int E = (int)floorf(fmaxf(g1, g2));
    float cMx = 0.0f, cMy = 0.0f, cIx = 0.0f, cIy = 0.0f;
    float cDx = exp2_hw(g1 - (float)E), cDy = exp2_hw(g2 - (float)E);
    float emM = 0.0f, emI = 0.0f, emD = 0.0f;
    float pM = lane0 ? 1.0f : 0.0f;   // with pE=0: PM = 2^-E at step 1 (= fM[0][0])
    float pI = 0.0f, pD = 0.0f; int pE = 0;
    float u = 0.0f; int EI0 = 0;
    int symq = 0;

    // 48 groups x 4 steps (s = 1..192). Fill g=0..15 (s 1..64, masked),
    // steady g=16..31 (s 65..128, mask-free), drain g=32..47 (masked, no tokens).
    #pragma unroll 1
    for (int g = 0; g < 16; ++g) {          // FILL
        const int a0 = __builtin_amdgcn_readlane(ts.x, 2*g);
        const int a1 = __builtin_amdgcn_readlane(ts.y, 2*g);
        const int a2 = __builtin_amdgcn_readlane(ts.z, 2*g);
        const int a3 = __builtin_amdgcn_readlane(ts.w, 2*g);
        const int b0 = __builtin_amdgcn_readlane(ts.x, 2*g+1);
        const int b1 = __builtin_amdgcn_readlane(ts.y, 2*g+1);
        const int b2 = __builtin_amdgcn_readlane(ts.z, 2*g+1);
        const int b3 = __builtin_amdgcn_readlane(ts.w, 2*g+1);
        STEP(a0 | (a1 << 2), g == 0, 1, 4*g);
        STEP(a2 | (a3 << 2), false,  1, 4*g + 1);
        STEP(b0 | (b1 << 2), false,  1, 4*g + 2);
        STEP(b2 | (b3 << 2), false,  1, 4*g + 3);
        RESCALE;
    }
    #pragma unroll 1
    for (int g = 16; g < 32; ++g) {         // STEADY (all lanes active)
        const int a0 = __builtin_amdgcn_readlane(ts.x, 2*g);
        const int a1 = __builtin_amdgcn_readlane(ts.y, 2*g);
        const int a2 = __builtin_amdgcn_readlane(ts.z, 2*g);
        const int a3 = __builtin_amdgcn_readlane(ts.w, 2*g);
        const int b0 = __builtin_amdgcn_readlane(ts.x, 2*g+1);
        const int b1 = __builtin_amdgcn_readlane(ts.y, 2*g+1);
        const int b2 = __builtin_amdgcn_readlane(ts.z, 2*g+1);
        const int b3 = __builtin_amdgcn_readlane(ts.w, 2*g+1);
        STEP(a0 | (a1 << 2), false, 0, 4*g);
        STEP(a2 | (a3 << 2), false, 0, 4*g + 1);
        STEP(b0 | (b1 << 2), false, 0, 4*g + 2);
        STEP(b2 | (b3 << 2), false, 0, 4*g + 3);
        RESCALE;
    }
    #pragma unroll 1
    for (int g = 32; g < 48; ++g) {         // DRAIN (no fresh tokens needed)
        STEP(0, false, 1, 4*g);
        STEP(0, false, 1, 4*g + 1);
        STEP(0, false, 1, 4*g + 2);
        STEP(0, false, 1, 4*g + 3);
        RESCALE;
    }

    // lane 63 holds k=127,128 @ col 256; y = k=128.
    const float fin = fmaf(tKdm, cDy, fmaf(tKim, cIy, tKmm*cMy));
    if (i == 63) nll_out[b] = -(log2_hw(fin) + (float)E)*LN2;
}

__global__ __launch_bounds__(256) void phmm_finish(const float* __restrict__ nll,
                                                   const float* __restrict__ mus,
                                                   const float* __restrict__ logvars,
                                                   float* __restrict__ out)
{
    const int tid = threadIdx.x;
    float acc = 0.0f;
    for (int idx = tid; idx < 512; idx += 256) acc += nll[idx];
    for (int idx = tid; idx < 8192; idx += 256) {
        const float mu = mus[idx], lv = logvars[idx];
        acc -= 0.5f * (1.0f + lv - mu * mu - exp2_hw(lv * LOG2E));
    }
    #pragma unroll
    for (int off = 32; off >= 1; off >>= 1) acc += __shfl_down(acc, off);
    __shared__ float red[4];
    if ((tid & 63) == 0) red[tid >> 6] = acc;
    __syncthreads();
    if (tid == 0) out[0] = (red[0] + red[1] + red[2] + red[3]) * (1.0f / 512.0f);
}

extern "C" void kernel_launch(void* const* d_in, const int* in_sizes, int n_in,
                              void* d_out, int out_size, void* d_ws, size_t ws_size,
                              hipStream_t stream)
{
    const int*   tokens  = (const int*)d_in[0];   // (512, 256) int32
    const float* trans   = (const float*)d_in[1]; // (512, 129, 7) f32
    const float* emis    = (const float*)d_in[2]; // (512, 128, 4) f32
    const float* mus     = (const float*)d_in[3]; // (512, 16) f32
    const float* logvars = (const float*)d_in[4]; // (512, 16) f32
    float* nll = (float*)d_ws;                    // 512 floats scratch

    phmm_fwd<<<dim3(512), dim3(64), 0, stream>>>(tokens, trans, emis, nll);
    phmm_finish<<<dim3(1), dim3(256), 0, stream>>>(nll, mus, logvars, (float*)d_out);
}